// Round 12
// baseline (375.053 us; speedup 1.0000x reference)
//
#include <hip/hip_runtime.h>
#include <cmath>

#define KSPLIT 8
#define ELL_ST 80   // max degree capacity; Poisson(16) tail beyond 80 ~ 1e-30
#define NSLOT 32    // stats slots (contention spreading)

typedef __attribute__((ext_vector_type(8))) short short8;
typedef __attribute__((ext_vector_type(4))) float float4v;

static __device__ __forceinline__ unsigned short f2bf(float f){
  union { float f; unsigned u; } c; c.f = f;
  unsigned r = c.u + 0x7fff + ((c.u >> 16) & 1);   // RNE
  return (unsigned short)(r >> 16);
}
static __device__ __forceinline__ float u2f(unsigned u){
  union { unsigned u; float f; } c; c.u = u; return c.f;
}
static __device__ __forceinline__ float silu(float y){ return y/(1.f+__expf(-y)); }

// BN affine coef {scale[128], shift[128]} from NSLOT-slot stats into LDS
static __device__ __forceinline__ void coef_prologue(const float* __restrict__ stats,
                                                     const float* __restrict__ gamma,
                                                     const float* __restrict__ beta,
                                                     float invM, float* lds, int tbase){
  int t = threadIdx.x - tbase;
  if(t >= 0 && t < 128){
    float s = 0.f, q = 0.f;
    #pragma unroll
    for(int k=0;k<NSLOT;k++){ s += stats[k*128+t]; q += stats[NSLOT*128 + k*128+t]; }
    float m = s*invM;
    float v = q*invM - m*m;
    float sc = gamma[t]*rsqrtf(v + 1e-5f);
    lds[t] = sc;
    lds[128+t] = beta[t] - m*sc;
  }
}

// ------- ELL build + 5 weight transposes + x->bf16 convert, ONE launch -------
__global__ void k_fill_wt(const int* __restrict__ src, const int* __restrict__ dst,
                          int* __restrict__ cursor, int* __restrict__ esrc, int E,
                          const float* __restrict__ w1a, const float* __restrict__ w1b,
                          const float* __restrict__ wp1, const float* __restrict__ w2a,
                          const float* __restrict__ w2b,
                          unsigned short* __restrict__ t1a, unsigned short* __restrict__ t1b,
                          unsigned short* __restrict__ tp1, unsigned short* __restrict__ t2a,
                          unsigned short* __restrict__ t2b,
                          const float* __restrict__ xin, unsigned short* __restrict__ xb,
                          int NX, int CIN){
  int i = blockIdx.x*256 + threadIdx.x;
  if(i < E){
    int d = dst[i];
    int p = atomicAdd(&cursor[d], 1);
    if(p < ELL_ST) esrc[(size_t)d*ELL_ST + p] = src[i];
  } else {
    int j = i - E;
    int n1 = CIN*128, n2 = 128*128;
    if(j >= 0 && j < n1){
      int k = j >> 7, c = j & 127;
      t1a[(size_t)c*CIN + k] = f2bf(w1a[j]);
    } else if(j >= n1 && j < n1+n2){
      int jj = j - n1; int k = jj >> 7, c = jj & 127;
      t1b[(size_t)c*128 + k] = f2bf(w1b[jj]);
    } else if(j >= n1+n2 && j < n1+2*n2){
      int jj = j - n1 - n2; int k = jj >> 7, c = jj & 127;
      tp1[(size_t)c*128 + k] = f2bf(wp1[jj]);
    } else if(j >= n1+2*n2 && j < n1+3*n2){
      int jj = j - n1 - 2*n2; int k = jj >> 7, c = jj & 127;
      t2a[(size_t)c*128 + k] = f2bf(w2a[jj]);
    } else if(j >= n1+3*n2 && j < n1+4*n2){
      int jj = j - n1 - 3*n2; int k = jj >> 7, c = jj & 127;
      t2b[(size_t)c*128 + k] = f2bf(w2b[jj]);
    } else if(j >= n1+4*n2 && j < n1+4*n2+NX){
      int jj = j - n1 - 4*n2;
      xb[jj] = f2bf(xin[jj]);          // bit-identical: gemm would f2bf anyway
    }
  }
}

// ---------------- MFMA GEMM: Cb(bf16)[M,128] = act(A)[M,K] @ Bt[128,K]^T, 64x128 tile -------
template<bool ABF16>
__global__ void k_gemm_mfma(const void* __restrict__ A, const void* __restrict__ A2,
                            const unsigned short* __restrict__ Bt,
                            unsigned short* __restrict__ Cb,
                            unsigned short* __restrict__ Hout, int M, int K,
                            const int* __restrict__ rowdeg,
                            const float* __restrict__ rowscale,
                            const float* __restrict__ stA, const float* __restrict__ gA,
                            const float* __restrict__ beA,
                            const float* __restrict__ stB, const float* __restrict__ gB,
                            const float* __restrict__ beB, float invM){
  __shared__ unsigned short Abf[64][40];
  __shared__ unsigned short Bbf[128][40];
  __shared__ float lcA[256], lcB[256];
  int tid = threadIdx.x;
  if(stA) coef_prologue(stA, gA, beA, invM, lcA, 0);
  if(stB) coef_prologue(stB, gB, beB, invM, lcB, 128);
  if(stA || stB) __syncthreads();
  int wv = tid >> 6, lane = tid & 63;
  int quad = lane >> 4, l16 = lane & 15;
  int row0 = blockIdx.x*64;
  int sr = tid >> 2, sk = (tid & 3)*8;        // A staging: row, k-offset
  int srb = tid >> 1, skb = (tid & 1)*16;     // B staging: row (out col), k-offset
  float4v acc[8] = {};
  for(int kt=0; kt<K; kt+=32){
    uint4 pk;
    if(ABF16){
      const unsigned short* ap = (const unsigned short*)A + (size_t)(row0+sr)*K + kt + sk;
      uint4 u = *(const uint4*)ap;
      if(stA){
        float va[8];
        va[0]=u2f(u.x<<16); va[1]=u2f(u.x&0xffff0000u);
        va[2]=u2f(u.y<<16); va[3]=u2f(u.y&0xffff0000u);
        va[4]=u2f(u.z<<16); va[5]=u2f(u.z&0xffff0000u);
        va[6]=u2f(u.w<<16); va[7]=u2f(u.w&0xffff0000u);
        if(stB){
          const unsigned short* bp = (const unsigned short*)A2 + (size_t)(row0+sr)*K + kt + sk;
          uint4 v = *(const uint4*)bp;
          float vb[8];
          vb[0]=u2f(v.x<<16); vb[1]=u2f(v.x&0xffff0000u);
          vb[2]=u2f(v.y<<16); vb[3]=u2f(v.y&0xffff0000u);
          vb[4]=u2f(v.z<<16); vb[5]=u2f(v.z&0xffff0000u);
          vb[6]=u2f(v.w<<16); vb[7]=u2f(v.w&0xffff0000u);
          #pragma unroll
          for(int i=0;i<8;i++){
            int c = kt+sk+i;
            va[i] = silu(lcA[c]*va[i] + lcA[128+c]) + silu(lcB[c]*vb[i] + lcB[128+c]);
          }
        } else {
          #pragma unroll
          for(int i=0;i<8;i++){
            int c = kt+sk+i;
            va[i] = silu(lcA[c]*va[i] + lcA[128+c]);
          }
        }
        pk.x = (unsigned)f2bf(va[0]) | ((unsigned)f2bf(va[1])<<16);
        pk.y = (unsigned)f2bf(va[2]) | ((unsigned)f2bf(va[3])<<16);
        pk.z = (unsigned)f2bf(va[4]) | ((unsigned)f2bf(va[5])<<16);
        pk.w = (unsigned)f2bf(va[6]) | ((unsigned)f2bf(va[7])<<16);
      } else {
        pk = u;                                  // pass-through (values already bf16)
      }
    } else {
      const float* ap = (const float*)A + (size_t)(row0+sr)*K + kt + sk;
      float va[8];
      *(float4*)&va[0] = *(const float4*)ap;
      *(float4*)&va[4] = *(const float4*)(ap+4);
      if(stA){
        #pragma unroll
        for(int i=0;i<8;i++){
          int c = kt+sk+i;
          va[i] = silu(lcA[c]*va[i] + lcA[128+c]);
        }
      }
      pk.x = (unsigned)f2bf(va[0]) | ((unsigned)f2bf(va[1])<<16);
      pk.y = (unsigned)f2bf(va[2]) | ((unsigned)f2bf(va[3])<<16);
      pk.z = (unsigned)f2bf(va[4]) | ((unsigned)f2bf(va[5])<<16);
      pk.w = (unsigned)f2bf(va[6]) | ((unsigned)f2bf(va[7])<<16);
    }
    *(uint4*)&Abf[sr][sk] = pk;
    if(Hout)
      *(uint4*)&Hout[(size_t)(row0+sr)*128 + kt + sk] = pk;   // K==128 when used
    *(uint4*)&Bbf[srb][skb]   = *(const uint4*)&Bt[(size_t)srb*K + kt + skb];
    *(uint4*)&Bbf[srb][skb+8] = *(const uint4*)&Bt[(size_t)srb*K + kt + skb + 8];
    __syncthreads();
    short8 af = *(const short8*)&Abf[wv*16 + l16][quad*8];
    #pragma unroll
    for(int t=0;t<8;t++){
      short8 bf = *(const short8*)&Bbf[t*16 + l16][quad*8];
      acc[t] = __builtin_amdgcn_mfma_f32_16x16x32_bf16(af, bf, acc[t], 0, 0, 0);
    }
    __syncthreads();
  }
  float scr[4];
  #pragma unroll
  for(int r=0;r<4;r++){
    int grow = row0 + wv*16 + quad*4 + r;
    scr[r] = rowdeg ? rsqrtf((float)rowdeg[grow] + 1.0f) : (rowscale ? rowscale[grow] : 1.f);
  }
  #pragma unroll
  for(int t=0;t<8;t++){
    #pragma unroll
    for(int r=0;r<4;r++){
      int grow = row0 + wv*16 + quad*4 + r;
      Cb[(size_t)grow*128 + t*16 + l16] = f2bf(acc[t][r]*scr[r]);
    }
  }
}

// ---------------- ELL-gather (R8 form): wave/node, 8B loads, 4 accumulators ------
template<bool DO_SOFTMAX, bool GCN, bool STATS, bool BF16OUT>
__global__ void k_gather(const int* __restrict__ degc, const int* __restrict__ esrc,
                         const unsigned short* __restrict__ h16,
                         const float* __restrict__ bias, float* __restrict__ out,
                         float* __restrict__ stats){
  __shared__ float lsum[4][128];
  __shared__ float lsq[4][128];
  int wave = threadIdx.x >> 6;
  int lane = threadIdx.x & 63;
  int bid = blockIdx.x;
  int d = ((bid & 7) << 12) | ((bid >> 3) << 2) | wave;
  int grp = lane >> 5;
  int c4 = (lane & 31)*4;
  int dgr = degc[d];                                // true degree (for dinv)
  int cnt = dgr > ELL_ST ? ELL_ST : dgr;
  cnt = __builtin_amdgcn_readfirstlane(cnt);        // scalar loop bounds
  const int* row = esrc + (size_t)d*ELL_ST;

  auto loadrow = [&](int s)->float4{
    uint2 u = *(const uint2*)&h16[(size_t)s*128 + c4];
    float4 v;
    v.x = u2f(u.x << 16); v.y = u2f(u.x & 0xffff0000u);
    v.z = u2f(u.y << 16); v.w = u2f(u.y & 0xffff0000u);
    return v;
  };

  float4 a0 = {0.f,0.f,0.f,0.f}, a1 = {0.f,0.f,0.f,0.f};
  float4 a2 = {0.f,0.f,0.f,0.f}, a3 = {0.f,0.f,0.f,0.f};
  if(GCN && grp == 0)
    a0 = loadrow(d);                                  // self loop
  for(int base=0; base<cnt; base+=32){
    int m = cnt - base; if(m > 32) m = 32;            // scalar
    int idx = (lane < m) ? row[base + lane] : 0;
    int full = m & ~7;                                // full groups of 8 edges
    int j0 = 0;
    for(; j0 < full; j0 += 8){                        // fast path: no guards
      int s0 = __shfl(idx, j0+grp);
      int s1 = __shfl(idx, j0+grp+2);
      int s2 = __shfl(idx, j0+grp+4);
      int s3 = __shfl(idx, j0+grp+6);
      float4 v0 = loadrow(s0);
      float4 v1 = loadrow(s1);
      float4 v2 = loadrow(s2);
      float4 v3 = loadrow(s3);
      a0.x+=v0.x; a0.y+=v0.y; a0.z+=v0.z; a0.w+=v0.w;
      a1.x+=v1.x; a1.y+=v1.y; a1.z+=v1.z; a1.w+=v1.w;
      a2.x+=v2.x; a2.y+=v2.y; a2.z+=v2.z; a2.w+=v2.w;
      a3.x+=v3.x; a3.y+=v3.y; a3.z+=v3.z; a3.w+=v3.w;
    }
    if(j0 < m){                                       // guarded tail (<8 edges)
      int jj0 = j0+grp, jj1 = j0+grp+2, jj2 = j0+grp+4, jj3 = j0+grp+6;
      int s0 = __shfl(idx, jj0 < m ? jj0 : 0);
      int s1 = __shfl(idx, jj1 < m ? jj1 : 0);
      int s2 = __shfl(idx, jj2 < m ? jj2 : 0);
      int s3 = __shfl(idx, jj3 < m ? jj3 : 0);
      if(jj0 < m){ float4 v = loadrow(s0);
        a0.x+=v.x; a0.y+=v.y; a0.z+=v.z; a0.w+=v.w; }
      if(jj1 < m){ float4 v = loadrow(s1);
        a1.x+=v.x; a1.y+=v.y; a1.z+=v.z; a1.w+=v.w; }
      if(jj2 < m){ float4 v = loadrow(s2);
        a2.x+=v.x; a2.y+=v.y; a2.z+=v.z; a2.w+=v.w; }
      if(jj3 < m){ float4 v = loadrow(s3);
        a3.x+=v.x; a3.y+=v.y; a3.z+=v.z; a3.w+=v.w; }
    }
  }
  float4 acc;
  acc.x = (a0.x+a1.x)+(a2.x+a3.x);
  acc.y = (a0.y+a1.y)+(a2.y+a3.y);
  acc.z = (a0.z+a1.z)+(a2.z+a3.z);
  acc.w = (a0.w+a1.w)+(a2.w+a3.w);
  acc.x += __shfl_xor(acc.x, 32);
  acc.y += __shfl_xor(acc.y, 32);
  acc.z += __shfl_xor(acc.z, 32);
  acc.w += __shfl_xor(acc.w, 32);
  float4 val = acc;
  if(GCN){
    float dv = rsqrtf((float)dgr + 1.0f);
    float4 bi = *(const float4*)&bias[c4];
    val.x = dv*acc.x + bi.x; val.y = dv*acc.y + bi.y;
    val.z = dv*acc.z + bi.z; val.w = dv*acc.w + bi.w;
  }
  if(DO_SOFTMAX){
    float mx = fmaxf(fmaxf(val.x,val.y), fmaxf(val.z,val.w));
    #pragma unroll
    for(int o=1;o<32;o<<=1) mx = fmaxf(mx, __shfl_xor(mx,o));
    float4 e; e.x=__expf(val.x-mx); e.y=__expf(val.y-mx);
    e.z=__expf(val.z-mx); e.w=__expf(val.w-mx);
    float s = e.x+e.y+e.z+e.w;
    #pragma unroll
    for(int o=1;o<32;o<<=1) s += __shfl_xor(s,o);
    float inv = 1.f/s;
    val.x=e.x*inv; val.y=e.y*inv; val.z=e.z*inv; val.w=e.w*inv;
  }
  if(grp == 0){
    if(BF16OUT){
      unsigned short* o16 = (unsigned short*)out;
      uint2 w;
      w.x = (unsigned)f2bf(val.x) | ((unsigned)f2bf(val.y)<<16);
      w.y = (unsigned)f2bf(val.z) | ((unsigned)f2bf(val.w)<<16);
      *(uint2*)&o16[(size_t)d*128 + c4] = w;
    } else {
      *(float4*)&out[(size_t)d*128 + c4] = val;
    }
  }
  if(STATS){
    if(grp == 0){
      *(float4*)&lsum[wave][c4] = val;
      float4 q; q.x=val.x*val.x; q.y=val.y*val.y; q.z=val.z*val.z; q.w=val.w*val.w;
      *(float4*)&lsq[wave][c4] = q;
    }
    __syncthreads();
    int t = threadIdx.x;
    int slot = bid & (NSLOT-1);
    if(t < 128){
      float s = (lsum[0][t]+lsum[1][t]) + (lsum[2][t]+lsum[3][t]);
      atomicAdd(&stats[slot*128 + t], s);
    } else {
      int c = t - 128;
      float q = (lsq[0][c]+lsq[1][c]) + (lsq[2][c]+lsq[3][c]);
      atomicAdd(&stats[NSLOT*128 + slot*128 + c], q);
    }
  }
}

// ---------------- pool split-K, MFMA: part[k1][c] = sum_node s[node][k1] * q[node][c] ----
__global__ __launch_bounds__(256, 2)
void k_pool2(const unsigned short* __restrict__ P, const unsigned short* __restrict__ QH,
             const unsigned short* __restrict__ QT,
             float* __restrict__ part1, float* __restrict__ part2, int npg, int nb){
  __shared__ unsigned short sT[128][40];   // [k1][node], pad->80B rows (16B aligned)
  __shared__ unsigned short qT[128][40];   // [c][node]
  int tid = threadIdx.x;
  bool zq = (blockIdx.z == 0);                 // block-uniform
  const unsigned short* Q = zq ? QH : QT;
  int ks = blockIdx.x, b = blockIdx.y;
  int klen = npg / KSPLIT;                 // 128
  size_t base = ((size_t)b*npg + (size_t)ks*klen)*128;
  int wv = tid >> 6, lane = tid & 63;
  int quad = lane >> 4, l16 = lane & 15;
  int wr = (wv >> 1)*64, wc = (wv & 1)*64;       // wave quadrant of 128x128 out
  int arr = tid >> 7;                             // 0: stage sT, 1: stage qT
  int t7 = tid & 127;
  int sg = (t7 >> 4)*16;                          // 16-channel segment
  int sr2 = (t7 & 15)*2;                          // node pair
  float4v acc[4][4] = {};

  for(int c0 = 0; c0 < klen; c0 += 32){
    size_t i0 = base + (size_t)(c0+sr2)*128 + sg;
    const unsigned short* Sp = arr ? Q : P;
    unsigned short (*dstT)[40] = arr ? qT : sT;
    uint4 ua = *(const uint4*)&Sp[i0];
    uint4 ub = *(const uint4*)&Sp[i0+8];
    uint4 uc = *(const uint4*)&Sp[i0+128];
    uint4 ud = *(const uint4*)&Sp[i0+136];
    unsigned short lo[16], hi[16];
    *(uint4*)&lo[0]=ua; *(uint4*)&lo[8]=ub;
    *(uint4*)&hi[0]=uc; *(uint4*)&hi[8]=ud;
    #pragma unroll
    for(int j=0;j<16;j++)
      *(unsigned*)&dstT[sg+j][sr2] = (unsigned)lo[j] | ((unsigned)hi[j]<<16);
    __syncthreads();
    #pragma unroll
    for(int i=0;i<4;i++){
      short8 af = *(const short8*)&sT[wr + i*16 + l16][quad*8];
      #pragma unroll
      for(int j=0;j<4;j++){
        short8 bf = *(const short8*)&qT[wc + j*16 + l16][quad*8];
        acc[i][j] = __builtin_amdgcn_mfma_f32_16x16x32_bf16(af, bf, acc[i][j], 0, 0, 0);
      }
    }
    __syncthreads();
  }

  float* outp = (zq ? part1 : part2) + ((size_t)(ks*nb + b)*128)*128;
  #pragma unroll
  for(int i=0;i<4;i++)
    #pragma unroll
    for(int r=0;r<4;r++){
      int m = wr + i*16 + quad*4 + r;
      #pragma unroll
      for(int j=0;j<4;j++)
        outp[(size_t)m*128 + wc + j*16 + l16] = acc[i][j][r];
    }
}

// ---------------- FUSED dense layer, COLUMN-SPLIT, PARTIAL-FOLDING (grid = (4, B)): ----------
// No materialized x2/A2b/dinv2: dinv2 recomputed per block from p2 (pool_reduce2's exact sum
// order); ACT=false: Ain = p1, phase-1 staging sums the KSPLIT partials then f2bf (bit-
// identical to reading x2); ACT=true: Ain = dTa fp32 with BN+SiLU. Phase 2 stages
// f2bf(sum_ks p2) == A2b bits. All cross-block dataflow crosses dispatch boundaries.
template<bool ACT>
__global__ void k_dense2(const float* __restrict__ Ain, const float* __restrict__ p2,
                         const unsigned short* __restrict__ Wt,
                         const float* __restrict__ bias,
                         const float* __restrict__ stA, const float* __restrict__ gA,
                         const float* __restrict__ beA, float invM,
                         float* __restrict__ outp, float* __restrict__ stats){
  __shared__ unsigned short Abf[128][40];   // A rows (ph1) / A2 rows (ph2) x 32-chunk
  __shared__ unsigned short Bbf[32][40];    // W cols x 32-k chunk
  __shared__ unsigned short Xt[32][136];    // [c-local][m-swizzled]
  __shared__ float ssum[32], ssq[32];
  __shared__ float lc[256];
  __shared__ float dinvL[128];
  int tid = threadIdx.x;
  int cq = blockIdx.x, b = blockIdx.y;
  if(ACT) coef_prologue(stA, gA, beA, invM, lc, 0);
  if(tid < 32){ ssum[tid] = 0.f; ssq[tid] = 0.f; }
  // pre-phase: dinv2 rows for graph b (replicates pool_reduce2's sum order exactly)
  {
    int lane32 = tid & 31, rowg = tid >> 5;   // 8 rows in flight
    int c4l = lane32*4;
    for(int it=0; it<16; it++){
      int m = rowg + it*8;
      const float* q = p2 + (size_t)b*16384 + (size_t)m*128 + c4l;
      float4 s = *(const float4*)q;
      #pragma unroll
      for(int ks=1; ks<KSPLIT; ks++){
        float4 v = *(const float4*)(q + (size_t)ks*524288);
        s.x+=v.x; s.y+=v.y; s.z+=v.z; s.w+=v.w;
      }
      float rs = s.x+s.y+s.z+s.w;
      #pragma unroll
      for(int o=16;o>0;o>>=1) rs += __shfl_xor(rs, o);
      if(lane32 == 0) dinvL[m] = rsqrtf(rs + 1.0f);
    }
  }
  __syncthreads();
  int wv = tid >> 6, lane = tid & 63;
  int quad = lane >> 4, l16 = lane & 15;

  // ---- phase 1: X_cols = act(Ain[b]) @ Wt[cq cols] ----
  float4v acc[2][2] = {};
  int ar = tid >> 1, ak = (tid & 1)*16;          // A staging: row, 16-k block
  int wr_ = tid >> 2, wk = (tid & 3)*8;          // W staging: threads 0..127
  for(int kt=0; kt<128; kt+=32){
    float va[16];
    const float* q = Ain + (size_t)b*16384 + (size_t)ar*128 + kt + ak;
    *(float4*)&va[0]  = *(const float4*)q;
    *(float4*)&va[4]  = *(const float4*)(q+4);
    *(float4*)&va[8]  = *(const float4*)(q+8);
    *(float4*)&va[12] = *(const float4*)(q+12);
    if(!ACT){
      #pragma unroll
      for(int ks=1; ks<KSPLIT; ks++){
        const float* qq = q + (size_t)ks*524288;
        float vv[16];
        *(float4*)&vv[0]  = *(const float4*)qq;
        *(float4*)&vv[4]  = *(const float4*)(qq+4);
        *(float4*)&vv[8]  = *(const float4*)(qq+8);
        *(float4*)&vv[12] = *(const float4*)(qq+12);
        #pragma unroll
        for(int i=0;i<16;i++) va[i] += vv[i];
      }
    } else {
      #pragma unroll
      for(int i=0;i<16;i++){
        int c = kt+ak+i;
        va[i] = silu(lc[c]*va[i] + lc[128+c]);
      }
    }
    uint4 p0, p1;
    p0.x = (unsigned)f2bf(va[0])  | ((unsigned)f2bf(va[1])<<16);
    p0.y = (unsigned)f2bf(va[2])  | ((unsigned)f2bf(va[3])<<16);
    p0.z = (unsigned)f2bf(va[4])  | ((unsigned)f2bf(va[5])<<16);
    p0.w = (unsigned)f2bf(va[6])  | ((unsigned)f2bf(va[7])<<16);
    p1.x = (unsigned)f2bf(va[8])  | ((unsigned)f2bf(va[9])<<16);
    p1.y = (unsigned)f2bf(va[10]) | ((unsigned)f2bf(va[11])<<16);
    p1.z = (unsigned)f2bf(va[12]) | ((unsigned)f2bf(va[13])<<16);
    p1.w = (unsigned)f2bf(va[14]) | ((unsigned)f2bf(va[15])<<16);
    *(uint4*)&Abf[ar][ak]   = p0;
    *(uint4*)&Abf[ar][ak+8] = p1;
    if(tid < 128)
      *(uint4*)&Bbf[wr_][wk] = *(const uint4*)&Wt[(size_t)(cq*32 + wr_)*128 + kt + wk];
    __syncthreads();
    #pragma unroll
    for(int i=0;i<2;i++){
      short8 af = *(const short8*)&Abf[wv*32 + i*16 + l16][quad*8];
      #pragma unroll
      for(int j=0;j<2;j++){
        short8 bf = *(const short8*)&Bbf[j*16 + l16][quad*8];
        acc[i][j] = __builtin_amdgcn_mfma_f32_16x16x32_bf16(af, bf, acc[i][j], 0, 0, 0);
      }
    }
    __syncthreads();
  }
  #pragma unroll
  for(int i=0;i<2;i++){
    #pragma unroll
    for(int r=0;r<4;r++){
      int m = wv*32 + i*16 + quad*4 + r;
      float dv = dinvL[m];
      #pragma unroll
      for(int j=0;j<2;j++){
        int cc = j*16 + l16;
        int pm = ((((m>>3) + 2*(cc&3)) & 15) << 3) | (m & 7);
        Xt[cc][pm] = f2bf(acc[i][j][r]*dv);   // same value as unsplit version
      }
    }
  }
  __syncthreads();

  // ---- phase 2: out_cols = (sum_ks p2)[b] @ Xcols + residual ----
  float4v acc2[2][2] = {};
  for(int n0 = 0; n0 < 128; n0 += 32){
    {
      const float* q = p2 + (size_t)b*16384 + (size_t)(tid>>1)*128 + n0 + (tid&1)*16;
      float va[16];
      *(float4*)&va[0]  = *(const float4*)q;
      *(float4*)&va[4]  = *(const float4*)(q+4);
      *(float4*)&va[8]  = *(const float4*)(q+8);
      *(float4*)&va[12] = *(const float4*)(q+12);
      #pragma unroll
      for(int ks=1; ks<KSPLIT; ks++){
        const float* qq = q + (size_t)ks*524288;
        float vv[16];
        *(float4*)&vv[0]  = *(const float4*)qq;
        *(float4*)&vv[4]  = *(const float4*)(qq+4);
        *(float4*)&vv[8]  = *(const float4*)(qq+8);
        *(float4*)&vv[12] = *(const float4*)(qq+12);
        #pragma unroll
        for(int i=0;i<16;i++) va[i] += vv[i];
      }
      uint4 p0, p1;
      p0.x = (unsigned)f2bf(va[0])  | ((unsigned)f2bf(va[1])<<16);
      p0.y = (unsigned)f2bf(va[2])  | ((unsigned)f2bf(va[3])<<16);
      p0.z = (unsigned)f2bf(va[4])  | ((unsigned)f2bf(va[5])<<16);
      p0.w = (unsigned)f2bf(va[6])  | ((unsigned)f2bf(va[7])<<16);
      p1.x = (unsigned)f2bf(va[8])  | ((unsigned)f2bf(va[9])<<16);
      p1.y = (unsigned)f2bf(va[10]) | ((unsigned)f2bf(va[11])<<16);
      p1.z = (unsigned)f2bf(va[12]) | ((unsigned)f2bf(va[13])<<16);
      p1.w = (unsigned)f2bf(va[14]) | ((unsigned)f2bf(va[15])<<16);
      *(uint4*)&Abf[tid>>1][(tid&1)*16]     = p0;
      *(uint4*)&Abf[tid>>1][(tid&1)*16 + 8] = p1;
    }
    __syncthreads();
    #pragma unroll
    for(int i=0;i<2;i++){
      short8 af = *(const short8*)&Abf[wv*32 + i*16 + l16][quad*8];
      #pragma unroll
      for(int j=0;j<2;j++){
        int cc = j*16 + l16;
        int pcm = ((n0>>3) + quad + 2*(cc&3)) & 15;
        short8 bf = *(const short8*)&Xt[cc][pcm<<3];
        acc2[i][j] = __builtin_amdgcn_mfma_f32_16x16x32_bf16(af, bf, acc2[i][j], 0, 0, 0);
      }
    }
    __syncthreads();
  }

  float sv[2] = {}, sq[2] = {};
  #pragma unroll
  for(int i=0;i<2;i++){
    #pragma unroll
    for(int r=0;r<4;r++){
      int m = wv*32 + i*16 + quad*4 + r;
      float dv = dinvL[m];
      #pragma unroll
      for(int j=0;j<2;j++){
        int cc = j*16 + l16;
        int pm = ((((m>>3) + 2*(cc&3)) & 15) << 3) | (m & 7);
        float xr = u2f((unsigned)Xt[cc][pm] << 16);
        float v = dv*(acc2[i][j][r] + xr) + bias[cq*32 + cc];
        outp[((size_t)(b*128 + m))*128 + cq*32 + cc] = v;
        sv[j] += v; sq[j] += v*v;
      }
    }
  }
  #pragma unroll
  for(int j=0;j<2;j++){
    int cc = j*16 + l16;
    atomicAdd(&ssum[cc], sv[j]);
    atomicAdd(&ssq[cc], sq[j]);
  }
  __syncthreads();
  if(tid < 32){
    int slot = b & (NSLOT-1);                  // per-graph slot; channels disjoint per cq
    atomicAdd(&stats[slot*128 + cq*32 + tid], ssum[tid]);
    atomicAdd(&stats[NSLOT*128 + slot*128 + cq*32 + tid], ssq[tid]);
  }
}

// ---------------- final (merged): per-graph BN+SiLU reduce, logits, log-softmax ----------------
__global__ void k_final(const float* __restrict__ dTa, const float* __restrict__ dTb,
                        const float* __restrict__ stA, const float* __restrict__ gA,
                        const float* __restrict__ beA,
                        const float* __restrict__ stB, const float* __restrict__ gB,
                        const float* __restrict__ beB, float invMc,
                        const float* __restrict__ wl, const float* __restrict__ bl,
                        float* __restrict__ out, int K1n, int Cc, float inv_k2,
                        int OUTc, int zero_idx){
  __shared__ float lcA[256], lcB[256];
  __shared__ float red[256];
  __shared__ float gsh[128];
  __shared__ float logits[32];
  __shared__ float mred, lred;
  coef_prologue(stA, gA, beA, invMc, lcA, 0);
  coef_prologue(stB, gB, beB, invMc, lcB, 128);
  __syncthreads();
  int b = blockIdx.x;
  int tid = threadIdx.x;
  int c = tid & 127, rh = tid >> 7;   // 2 rows in flight
  const float* pa = dTa + (size_t)b*K1n*Cc;
  const float* pb = dTb + (size_t)b*K1n*Cc;
  float sa = lcA[c], ha = lcA[128+c], sb = lcB[c], hb = lcB[128+c];
  float acc = 0.f;
  for(int r = rh; r < K1n; r += 2){
    float ya = sa*pa[(size_t)r*Cc + c] + ha;
    float yb = sb*pb[(size_t)r*Cc + c] + hb;
    acc += silu(ya) + silu(yb);
  }
  red[tid] = acc;
  __syncthreads();
  if(tid < 128) gsh[tid] = (red[tid] + red[tid+128]) * inv_k2;
  __syncthreads();
  if(tid < OUTc){
    float l = bl[tid];
    for(int d2=0; d2<Cc; d2++) l += gsh[d2]*wl[d2*OUTc + tid];
    logits[tid] = l;
  }
  __syncthreads();
  if(tid==0){
    float m = -1e30f;
    for(int o=0;o<OUTc;o++) m = fmaxf(m, logits[o]);
    float s = 0.f;
    for(int o=0;o<OUTc;o++) s += __expf(logits[o]-m);
    mred = m; lred = logf(s);
  }
  __syncthreads();
  if(tid < OUTc) out[b*OUTc + tid] = logits[tid] - mred - lred;
  if(b==0 && tid==0 && zero_idx >= 0) out[zero_idx] = 0.f;
}

// ---------------- launch ----------------
extern "C" void kernel_launch(void* const* d_in, const int* in_sizes, int n_in,
                              void* d_out, int out_size, void* d_ws, size_t ws_size,
                              hipStream_t stream){
  const float* x    = (const float*)d_in[0];
  const int*   ei   = (const int*)d_in[1];
  const float* w1a  = (const float*)d_in[4];
  const float* b1a  = (const float*)d_in[5];
  const float* g1a  = (const float*)d_in[6];
  const float* be1a = (const float*)d_in[7];
  const float* w1b  = (const float*)d_in[8];
  const float* b1b  = (const float*)d_in[9];
  const float* g1b  = (const float*)d_in[10];
  const float* be1b = (const float*)d_in[11];
  const float* wp1  = (const float*)d_in[12];
  const float* bp1  = (const float*)d_in[13];
  const float* w2a  = (const float*)d_in[14];
  const float* b2a  = (const float*)d_in[15];
  const float* g2a  = (const float*)d_in[16];
  const float* be2a = (const float*)d_in[17];
  const float* w2b  = (const float*)d_in[18];
  const float* b2b  = (const float*)d_in[19];
  const float* g2b  = (const float*)d_in[20];
  const float* be2b = (const float*)d_in[21];
  const float* wl   = (const float*)d_in[24];
  const float* bl   = (const float*)d_in[25];
  float* out = (float*)d_out;

  const int C_   = in_sizes[5];            // 128
  const int CIN_ = in_sizes[4]/C_;         // 64
  const int N    = in_sizes[0]/CIN_;       // 32768
  const int E    = in_sizes[1]/2;          // 524288
  const int B_   = in_sizes[3]-1;          // 32
  const int NPG_ = N/B_;                   // 1024
  const int K1_  = in_sizes[13];           // 128
  const int K2_  = in_sizes[23];           // 32
  const int OUTc = in_sizes[25];           // 10
  const int M2   = B_*K1_;                 // 4096
  const int total = M2*C_;                 // 524288
  const int NX   = N*CIN_;                 // 2097152

  const int* srcI = ei;
  const int* dstI = ei + E;

  float* ws = (float*)d_ws;
  size_t o = 0;
  unsigned short* bufW = (unsigned short*)(ws + o); o += (size_t)N*C_/2;   // bf16 gemm out
  unsigned short* bufA = (unsigned short*)(ws + o); o += (size_t)N*C_/2;   // 1a gather out (bf16)
  unsigned short* bufB = (unsigned short*)(ws + o); o += (size_t)N*C_/2;   // 1b gather out (bf16)
  unsigned short* bufS = (unsigned short*)(ws + o); o += (size_t)N*C_/2;   // s (bf16)
  unsigned short* bufT = (unsigned short*)(ws + o); o += (size_t)N*C_/2;   // t = A s (bf16)
  unsigned short* bufH = (unsigned short*)(ws + o); o += (size_t)N*C_/2;   // fused h (bf16)
  unsigned short* xbf  = (unsigned short*)(ws + o); o += (size_t)NX/2 + 64; // x (bf16)
  float* dTa   = ws + o; o += (size_t)total;   // dense layer a out
  float* dTb   = ws + o; o += (size_t)total;   // dense layer b out
  // zero block: 4 x NSLOT-slot stats + cursor — ONE memset
  float* st1a  = ws + o; o += 2*NSLOT*128;
  float* st1b  = ws + o; o += 2*NSLOT*128;
  float* stDa  = ws + o; o += 2*NSLOT*128;
  float* stDb  = ws + o; o += 2*NSLOT*128;
  int* cursor  = (int*)(ws + o); o += (size_t)N;
  float* part  = ws + o; o += (size_t)KSPLIT*total;
  float* part2 = ws + o; o += (size_t)KSPLIT*total;
  unsigned short* wt1a = (unsigned short*)(ws + o); o += (size_t)CIN_*C_/2 + 64;
  unsigned short* wt1b = (unsigned short*)(ws + o); o += (size_t)C_*C_/2 + 64;
  unsigned short* wtp1 = (unsigned short*)(ws + o); o += (size_t)C_*C_/2 + 64;
  unsigned short* wt2a = (unsigned short*)(ws + o); o += (size_t)C_*C_/2 + 64;
  unsigned short* wt2b = (unsigned short*)(ws + o); o += (size_t)C_*C_/2 + 64;
  int* esrc    = (int*)(ws + o); o += (size_t)N*ELL_ST;
  (void)ws_size; (void)n_in;

  dim3 blk256(256);
  auto g1 = [](int n){ return dim3((unsigned)((n+255)/256)); };
  const float invN = 1.0f/N, invM2 = 1.0f/M2;

  // ---- setup: one memset (stats x4 + cursor), then ELL fill + wt transposes + x->bf16 ----
  hipMemsetAsync(st1a, 0, (size_t)4*2*NSLOT*128*sizeof(float) + (size_t)N*sizeof(int), stream);
  k_fill_wt<<<g1(E + CIN_*C_ + 4*C_*C_ + NX), blk256, 0, stream>>>(srcI, dstI, cursor, esrc, E,
      w1a, w1b, wp1, w2a, w2b, wt1a, wt1b, wtp1, wt2a, wt2b, x, xbf, NX, CIN_);

  dim3 gath((unsigned)(N/4));
  dim3 gmm((unsigned)(N/64));

  // ---- layer 1a (bf16 A pass-through) ----
  k_gemm_mfma<true><<<gmm, blk256, 0, stream>>>(xbf, nullptr, wt1a, bufW, nullptr, N, CIN_, cursor,
      nullptr, nullptr, nullptr, nullptr, nullptr, nullptr, nullptr, 0.f);
  k_gather<false,true,true,true><<<gath, blk256, 0, stream>>>(cursor, esrc, bufW, b1a, (float*)bufA, st1a);

  // ---- layer 1b (coef1a inlined; bf16 A) ----
  k_gemm_mfma<true><<<gmm, blk256, 0, stream>>>(bufA, nullptr, wt1b, bufW, nullptr, N, C_, cursor,
      nullptr, st1a, g1a, be1a, nullptr, nullptr, nullptr, invN);
  k_gather<false,true,true,true><<<gath, blk256, 0, stream>>>(cursor, esrc, bufW, b1b, (float*)bufB, st1b);

  // ---- pool: s = softmax(gcn(h, wp1, bp1)) bf16; h (fused act) dumped bf16 as side-product ----
  k_gemm_mfma<true><<<gmm, blk256, 0, stream>>>(bufA, bufB, wtp1, bufW, bufH, N, C_, cursor,
      nullptr, st1a, g1a, be1a, st1b, g1b, be1b, invN);
  k_gather<true,true,false,true><<<gath, blk256, 0, stream>>>(cursor, esrc, bufW, bp1, (float*)bufS, nullptr);
  k_gather<false,false,false,true><<<gath, blk256, 0, stream>>>(cursor, esrc, bufS, nullptr, (float*)bufT, nullptr);

  // x2 = s^T h (z=0, from bf16 H) ; A2 = s^T t (z=1) — ONE MFMA launch into partials
  k_pool2<<<dim3(KSPLIT, B_, 2), blk256, 0, stream>>>(bufS, bufH, bufT,
      part, part2, NPG_, B_);

  // ---- dense stack: TWO fused kernels with partial-folding (pool_reduce2 eliminated) ----
  k_dense2<false><<<dim3(4, (unsigned)B_), blk256, 0, stream>>>(part, part2, wt2a, b2a,
      nullptr, nullptr, nullptr, 0.f, dTa, stDa);
  k_dense2<true><<<dim3(4, (unsigned)B_), blk256, 0, stream>>>(dTa, part2, wt2b, b2b,
      stDa, g2a, be2a, invM2, dTb, stDb);

  // ---- final: one kernel per graph — BN+SiLU reduce, logits, log-softmax ----
  int zero_idx = (out_size > B_*OUTc) ? B_*OUTc : -1;
  k_final<<<dim3((unsigned)B_), blk256, 0, stream>>>(dTa, dTb,
      stDa, g2a, be2a, stDb, g2b, be2b, invM2, wl, bl, out, K1_, C_, 1.0f/K2_,
      OUTc, zero_idx);
}

// Round 13
// 315.907 us; speedup vs baseline: 1.1872x; 1.1872x over previous
//
#include <hip/hip_runtime.h>
#include <cmath>

#define KSPLIT 8
#define ELL_ST 80   // max degree capacity; Poisson(16) tail beyond 80 ~ 1e-30
#define NSLOT 32    // stats slots (contention spreading)

typedef __attribute__((ext_vector_type(8))) short short8;
typedef __attribute__((ext_vector_type(4))) float float4v;

static __device__ __forceinline__ unsigned short f2bf(float f){
  union { float f; unsigned u; } c; c.f = f;
  unsigned r = c.u + 0x7fff + ((c.u >> 16) & 1);   // RNE
  return (unsigned short)(r >> 16);
}
static __device__ __forceinline__ float u2f(unsigned u){
  union { unsigned u; float f; } c; c.u = u; return c.f;
}
static __device__ __forceinline__ float silu(float y){ return y/(1.f+__expf(-y)); }

// BN affine coef {scale[128], shift[128]} from NSLOT-slot stats into LDS
static __device__ __forceinline__ void coef_prologue(const float* __restrict__ stats,
                                                     const float* __restrict__ gamma,
                                                     const float* __restrict__ beta,
                                                     float invM, float* lds, int tbase){
  int t = threadIdx.x - tbase;
  if(t >= 0 && t < 128){
    float s = 0.f, q = 0.f;
    #pragma unroll
    for(int k=0;k<NSLOT;k++){ s += stats[k*128+t]; q += stats[NSLOT*128 + k*128+t]; }
    float m = s*invM;
    float v = q*invM - m*m;
    float sc = gamma[t]*rsqrtf(v + 1e-5f);
    lds[t] = sc;
    lds[128+t] = beta[t] - m*sc;
  }
}

// ------- ELL build + 5 weight transposes + x->bf16 convert, ONE launch -------
__global__ void k_fill_wt(const int* __restrict__ src, const int* __restrict__ dst,
                          int* __restrict__ cursor, int* __restrict__ esrc, int E,
                          const float* __restrict__ w1a, const float* __restrict__ w1b,
                          const float* __restrict__ wp1, const float* __restrict__ w2a,
                          const float* __restrict__ w2b,
                          unsigned short* __restrict__ t1a, unsigned short* __restrict__ t1b,
                          unsigned short* __restrict__ tp1, unsigned short* __restrict__ t2a,
                          unsigned short* __restrict__ t2b,
                          const float* __restrict__ xin, unsigned short* __restrict__ xb,
                          int NX, int CIN){
  int i = blockIdx.x*256 + threadIdx.x;
  if(i < E){
    int d = dst[i];
    int p = atomicAdd(&cursor[d], 1);
    if(p < ELL_ST) esrc[(size_t)d*ELL_ST + p] = src[i];
  } else {
    int j = i - E;
    int n1 = CIN*128, n2 = 128*128;
    if(j >= 0 && j < n1){
      int k = j >> 7, c = j & 127;
      t1a[(size_t)c*CIN + k] = f2bf(w1a[j]);
    } else if(j >= n1 && j < n1+n2){
      int jj = j - n1; int k = jj >> 7, c = jj & 127;
      t1b[(size_t)c*128 + k] = f2bf(w1b[jj]);
    } else if(j >= n1+n2 && j < n1+2*n2){
      int jj = j - n1 - n2; int k = jj >> 7, c = jj & 127;
      tp1[(size_t)c*128 + k] = f2bf(wp1[jj]);
    } else if(j >= n1+2*n2 && j < n1+3*n2){
      int jj = j - n1 - 2*n2; int k = jj >> 7, c = jj & 127;
      t2a[(size_t)c*128 + k] = f2bf(w2a[jj]);
    } else if(j >= n1+3*n2 && j < n1+4*n2){
      int jj = j - n1 - 3*n2; int k = jj >> 7, c = jj & 127;
      t2b[(size_t)c*128 + k] = f2bf(w2b[jj]);
    } else if(j >= n1+4*n2 && j < n1+4*n2+NX){
      int jj = j - n1 - 4*n2;
      xb[jj] = f2bf(xin[jj]);          // bit-identical: gemm would f2bf anyway
    }
  }
}

// ---------------- MFMA GEMM: Cb(bf16)[M,128] = act(A)[M,K] @ Bt[128,K]^T, 64x128 tile -------
template<bool ABF16>
__global__ void k_gemm_mfma(const void* __restrict__ A, const void* __restrict__ A2,
                            const unsigned short* __restrict__ Bt,
                            unsigned short* __restrict__ Cb,
                            unsigned short* __restrict__ Hout, int M, int K,
                            const int* __restrict__ rowdeg,
                            const float* __restrict__ rowscale,
                            const float* __restrict__ stA, const float* __restrict__ gA,
                            const float* __restrict__ beA,
                            const float* __restrict__ stB, const float* __restrict__ gB,
                            const float* __restrict__ beB, float invM){
  __shared__ unsigned short Abf[64][40];
  __shared__ unsigned short Bbf[128][40];
  __shared__ float lcA[256], lcB[256];
  int tid = threadIdx.x;
  if(stA) coef_prologue(stA, gA, beA, invM, lcA, 0);
  if(stB) coef_prologue(stB, gB, beB, invM, lcB, 128);
  if(stA || stB) __syncthreads();
  int wv = tid >> 6, lane = tid & 63;
  int quad = lane >> 4, l16 = lane & 15;
  int row0 = blockIdx.x*64;
  int sr = tid >> 2, sk = (tid & 3)*8;        // A staging: row, k-offset
  int srb = tid >> 1, skb = (tid & 1)*16;     // B staging: row (out col), k-offset
  float4v acc[8] = {};
  for(int kt=0; kt<K; kt+=32){
    uint4 pk;
    if(ABF16){
      const unsigned short* ap = (const unsigned short*)A + (size_t)(row0+sr)*K + kt + sk;
      uint4 u = *(const uint4*)ap;
      if(stA){
        float va[8];
        va[0]=u2f(u.x<<16); va[1]=u2f(u.x&0xffff0000u);
        va[2]=u2f(u.y<<16); va[3]=u2f(u.y&0xffff0000u);
        va[4]=u2f(u.z<<16); va[5]=u2f(u.z&0xffff0000u);
        va[6]=u2f(u.w<<16); va[7]=u2f(u.w&0xffff0000u);
        if(stB){
          const unsigned short* bp = (const unsigned short*)A2 + (size_t)(row0+sr)*K + kt + sk;
          uint4 v = *(const uint4*)bp;
          float vb[8];
          vb[0]=u2f(v.x<<16); vb[1]=u2f(v.x&0xffff0000u);
          vb[2]=u2f(v.y<<16); vb[3]=u2f(v.y&0xffff0000u);
          vb[4]=u2f(v.z<<16); vb[5]=u2f(v.z&0xffff0000u);
          vb[6]=u2f(v.w<<16); vb[7]=u2f(v.w&0xffff0000u);
          #pragma unroll
          for(int i=0;i<8;i++){
            int c = kt+sk+i;
            va[i] = silu(lcA[c]*va[i] + lcA[128+c]) + silu(lcB[c]*vb[i] + lcB[128+c]);
          }
        } else {
          #pragma unroll
          for(int i=0;i<8;i++){
            int c = kt+sk+i;
            va[i] = silu(lcA[c]*va[i] + lcA[128+c]);
          }
        }
        pk.x = (unsigned)f2bf(va[0]) | ((unsigned)f2bf(va[1])<<16);
        pk.y = (unsigned)f2bf(va[2]) | ((unsigned)f2bf(va[3])<<16);
        pk.z = (unsigned)f2bf(va[4]) | ((unsigned)f2bf(va[5])<<16);
        pk.w = (unsigned)f2bf(va[6]) | ((unsigned)f2bf(va[7])<<16);
      } else {
        pk = u;                                  // pass-through (values already bf16)
      }
    } else {
      const float* ap = (const float*)A + (size_t)(row0+sr)*K + kt + sk;
      float va[8];
      *(float4*)&va[0] = *(const float4*)ap;
      *(float4*)&va[4] = *(const float4*)(ap+4);
      if(stA){
        #pragma unroll
        for(int i=0;i<8;i++){
          int c = kt+sk+i;
          va[i] = silu(lcA[c]*va[i] + lcA[128+c]);
        }
      }
      pk.x = (unsigned)f2bf(va[0]) | ((unsigned)f2bf(va[1])<<16);
      pk.y = (unsigned)f2bf(va[2]) | ((unsigned)f2bf(va[3])<<16);
      pk.z = (unsigned)f2bf(va[4]) | ((unsigned)f2bf(va[5])<<16);
      pk.w = (unsigned)f2bf(va[6]) | ((unsigned)f2bf(va[7])<<16);
    }
    *(uint4*)&Abf[sr][sk] = pk;
    if(Hout)
      *(uint4*)&Hout[(size_t)(row0+sr)*128 + kt + sk] = pk;   // K==128 when used
    *(uint4*)&Bbf[srb][skb]   = *(const uint4*)&Bt[(size_t)srb*K + kt + skb];
    *(uint4*)&Bbf[srb][skb+8] = *(const uint4*)&Bt[(size_t)srb*K + kt + skb + 8];
    __syncthreads();
    short8 af = *(const short8*)&Abf[wv*16 + l16][quad*8];
    #pragma unroll
    for(int t=0;t<8;t++){
      short8 bf = *(const short8*)&Bbf[t*16 + l16][quad*8];
      acc[t] = __builtin_amdgcn_mfma_f32_16x16x32_bf16(af, bf, acc[t], 0, 0, 0);
    }
    __syncthreads();
  }
  float scr[4];
  #pragma unroll
  for(int r=0;r<4;r++){
    int grow = row0 + wv*16 + quad*4 + r;
    scr[r] = rowdeg ? rsqrtf((float)rowdeg[grow] + 1.0f) : (rowscale ? rowscale[grow] : 1.f);
  }
  #pragma unroll
  for(int t=0;t<8;t++){
    #pragma unroll
    for(int r=0;r<4;r++){
      int grow = row0 + wv*16 + quad*4 + r;
      Cb[(size_t)grow*128 + t*16 + l16] = f2bf(acc[t][r]*scr[r]);
    }
  }
}

// ---------------- ELL-gather (R8 form): wave/node, 8B loads, 4 accumulators ------
template<bool DO_SOFTMAX, bool GCN, bool STATS, bool BF16OUT>
__global__ void k_gather(const int* __restrict__ degc, const int* __restrict__ esrc,
                         const unsigned short* __restrict__ h16,
                         const float* __restrict__ bias, float* __restrict__ out,
                         float* __restrict__ stats){
  __shared__ float lsum[4][128];
  __shared__ float lsq[4][128];
  int wave = threadIdx.x >> 6;
  int lane = threadIdx.x & 63;
  int bid = blockIdx.x;
  int d = ((bid & 7) << 12) | ((bid >> 3) << 2) | wave;
  int grp = lane >> 5;
  int c4 = (lane & 31)*4;
  int dgr = degc[d];                                // true degree (for dinv)
  int cnt = dgr > ELL_ST ? ELL_ST : dgr;
  cnt = __builtin_amdgcn_readfirstlane(cnt);        // scalar loop bounds
  const int* row = esrc + (size_t)d*ELL_ST;

  auto loadrow = [&](int s)->float4{
    uint2 u = *(const uint2*)&h16[(size_t)s*128 + c4];
    float4 v;
    v.x = u2f(u.x << 16); v.y = u2f(u.x & 0xffff0000u);
    v.z = u2f(u.y << 16); v.w = u2f(u.y & 0xffff0000u);
    return v;
  };

  float4 a0 = {0.f,0.f,0.f,0.f}, a1 = {0.f,0.f,0.f,0.f};
  float4 a2 = {0.f,0.f,0.f,0.f}, a3 = {0.f,0.f,0.f,0.f};
  if(GCN && grp == 0)
    a0 = loadrow(d);                                  // self loop
  for(int base=0; base<cnt; base+=32){
    int m = cnt - base; if(m > 32) m = 32;            // scalar
    int idx = (lane < m) ? row[base + lane] : 0;
    int full = m & ~7;                                // full groups of 8 edges
    int j0 = 0;
    for(; j0 < full; j0 += 8){                        // fast path: no guards
      int s0 = __shfl(idx, j0+grp);
      int s1 = __shfl(idx, j0+grp+2);
      int s2 = __shfl(idx, j0+grp+4);
      int s3 = __shfl(idx, j0+grp+6);
      float4 v0 = loadrow(s0);
      float4 v1 = loadrow(s1);
      float4 v2 = loadrow(s2);
      float4 v3 = loadrow(s3);
      a0.x+=v0.x; a0.y+=v0.y; a0.z+=v0.z; a0.w+=v0.w;
      a1.x+=v1.x; a1.y+=v1.y; a1.z+=v1.z; a1.w+=v1.w;
      a2.x+=v2.x; a2.y+=v2.y; a2.z+=v2.z; a2.w+=v2.w;
      a3.x+=v3.x; a3.y+=v3.y; a3.z+=v3.z; a3.w+=v3.w;
    }
    if(j0 < m){                                       // guarded tail (<8 edges)
      int jj0 = j0+grp, jj1 = j0+grp+2, jj2 = j0+grp+4, jj3 = j0+grp+6;
      int s0 = __shfl(idx, jj0 < m ? jj0 : 0);
      int s1 = __shfl(idx, jj1 < m ? jj1 : 0);
      int s2 = __shfl(idx, jj2 < m ? jj2 : 0);
      int s3 = __shfl(idx, jj3 < m ? jj3 : 0);
      if(jj0 < m){ float4 v = loadrow(s0);
        a0.x+=v.x; a0.y+=v.y; a0.z+=v.z; a0.w+=v.w; }
      if(jj1 < m){ float4 v = loadrow(s1);
        a1.x+=v.x; a1.y+=v.y; a1.z+=v.z; a1.w+=v.w; }
      if(jj2 < m){ float4 v = loadrow(s2);
        a2.x+=v.x; a2.y+=v.y; a2.z+=v.z; a2.w+=v.w; }
      if(jj3 < m){ float4 v = loadrow(s3);
        a3.x+=v.x; a3.y+=v.y; a3.z+=v.z; a3.w+=v.w; }
    }
  }
  float4 acc;
  acc.x = (a0.x+a1.x)+(a2.x+a3.x);
  acc.y = (a0.y+a1.y)+(a2.y+a3.y);
  acc.z = (a0.z+a1.z)+(a2.z+a3.z);
  acc.w = (a0.w+a1.w)+(a2.w+a3.w);
  acc.x += __shfl_xor(acc.x, 32);
  acc.y += __shfl_xor(acc.y, 32);
  acc.z += __shfl_xor(acc.z, 32);
  acc.w += __shfl_xor(acc.w, 32);
  float4 val = acc;
  if(GCN){
    float dv = rsqrtf((float)dgr + 1.0f);
    float4 bi = *(const float4*)&bias[c4];
    val.x = dv*acc.x + bi.x; val.y = dv*acc.y + bi.y;
    val.z = dv*acc.z + bi.z; val.w = dv*acc.w + bi.w;
  }
  if(DO_SOFTMAX){
    float mx = fmaxf(fmaxf(val.x,val.y), fmaxf(val.z,val.w));
    #pragma unroll
    for(int o=1;o<32;o<<=1) mx = fmaxf(mx, __shfl_xor(mx,o));
    float4 e; e.x=__expf(val.x-mx); e.y=__expf(val.y-mx);
    e.z=__expf(val.z-mx); e.w=__expf(val.w-mx);
    float s = e.x+e.y+e.z+e.w;
    #pragma unroll
    for(int o=1;o<32;o<<=1) s += __shfl_xor(s,o);
    float inv = 1.f/s;
    val.x=e.x*inv; val.y=e.y*inv; val.z=e.z*inv; val.w=e.w*inv;
  }
  if(grp == 0){
    if(BF16OUT){
      unsigned short* o16 = (unsigned short*)out;
      uint2 w;
      w.x = (unsigned)f2bf(val.x) | ((unsigned)f2bf(val.y)<<16);
      w.y = (unsigned)f2bf(val.z) | ((unsigned)f2bf(val.w)<<16);
      *(uint2*)&o16[(size_t)d*128 + c4] = w;
    } else {
      *(float4*)&out[(size_t)d*128 + c4] = val;
    }
  }
  if(STATS){
    if(grp == 0){
      *(float4*)&lsum[wave][c4] = val;
      float4 q; q.x=val.x*val.x; q.y=val.y*val.y; q.z=val.z*val.z; q.w=val.w*val.w;
      *(float4*)&lsq[wave][c4] = q;
    }
    __syncthreads();
    int t = threadIdx.x;
    int slot = bid & (NSLOT-1);
    if(t < 128){
      float s = (lsum[0][t]+lsum[1][t]) + (lsum[2][t]+lsum[3][t]);
      atomicAdd(&stats[slot*128 + t], s);
    } else {
      int c = t - 128;
      float q = (lsq[0][c]+lsq[1][c]) + (lsq[2][c]+lsq[3][c]);
      atomicAdd(&stats[NSLOT*128 + slot*128 + c], q);
    }
  }
}

// ---------------- pool split-K, MFMA: part[k1][c] = sum_node s[node][k1] * q[node][c] ----
__global__ __launch_bounds__(256, 2)
void k_pool2(const unsigned short* __restrict__ P, const unsigned short* __restrict__ QH,
             const unsigned short* __restrict__ QT,
             float* __restrict__ part1, float* __restrict__ part2, int npg, int nb){
  __shared__ unsigned short sT[128][40];   // [k1][node], pad->80B rows (16B aligned)
  __shared__ unsigned short qT[128][40];   // [c][node]
  int tid = threadIdx.x;
  bool zq = (blockIdx.z == 0);                 // block-uniform
  const unsigned short* Q = zq ? QH : QT;
  int ks = blockIdx.x, b = blockIdx.y;
  int klen = npg / KSPLIT;                 // 128
  size_t base = ((size_t)b*npg + (size_t)ks*klen)*128;
  int wv = tid >> 6, lane = tid & 63;
  int quad = lane >> 4, l16 = lane & 15;
  int wr = (wv >> 1)*64, wc = (wv & 1)*64;       // wave quadrant of 128x128 out
  int arr = tid >> 7;                             // 0: stage sT, 1: stage qT
  int t7 = tid & 127;
  int sg = (t7 >> 4)*16;                          // 16-channel segment
  int sr2 = (t7 & 15)*2;                          // node pair
  float4v acc[4][4] = {};

  for(int c0 = 0; c0 < klen; c0 += 32){
    size_t i0 = base + (size_t)(c0+sr2)*128 + sg;
    const unsigned short* Sp = arr ? Q : P;
    unsigned short (*dstT)[40] = arr ? qT : sT;
    uint4 ua = *(const uint4*)&Sp[i0];
    uint4 ub = *(const uint4*)&Sp[i0+8];
    uint4 uc = *(const uint4*)&Sp[i0+128];
    uint4 ud = *(const uint4*)&Sp[i0+136];
    unsigned short lo[16], hi[16];
    *(uint4*)&lo[0]=ua; *(uint4*)&lo[8]=ub;
    *(uint4*)&hi[0]=uc; *(uint4*)&hi[8]=ud;
    #pragma unroll
    for(int j=0;j<16;j++)
      *(unsigned*)&dstT[sg+j][sr2] = (unsigned)lo[j] | ((unsigned)hi[j]<<16);
    __syncthreads();
    #pragma unroll
    for(int i=0;i<4;i++){
      short8 af = *(const short8*)&sT[wr + i*16 + l16][quad*8];
      #pragma unroll
      for(int j=0;j<4;j++){
        short8 bf = *(const short8*)&qT[wc + j*16 + l16][quad*8];
        acc[i][j] = __builtin_amdgcn_mfma_f32_16x16x32_bf16(af, bf, acc[i][j], 0, 0, 0);
      }
    }
    __syncthreads();
  }

  float* outp = (zq ? part1 : part2) + ((size_t)(ks*nb + b)*128)*128;
  #pragma unroll
  for(int i=0;i<4;i++)
    #pragma unroll
    for(int r=0;r<4;r++){
      int m = wr + i*16 + quad*4 + r;
      #pragma unroll
      for(int j=0;j<4;j++)
        outp[(size_t)m*128 + wc + j*16 + l16] = acc[i][j][r];
    }
}

// x2 fp32 out; A2 emitted bf16 (feeds MFMA dense stack); dinv2 from fp32 row sums.
__global__ void k_pool_reduce2(const float* __restrict__ p1, const float* __restrict__ p2,
                               float* __restrict__ x2, unsigned short* __restrict__ A2b,
                               float* __restrict__ dinv2, int total){
  int i = blockIdx.x*256 + threadIdx.x;
  int half = total >> 2;
  if(i < half){
    float4 s = *(const float4*)&p1[(size_t)i*4];
    #pragma unroll
    for(int ks=1; ks<KSPLIT; ks++){
      float4 v = *(const float4*)&p1[(size_t)ks*total + (size_t)i*4];
      s.x+=v.x; s.y+=v.y; s.z+=v.z; s.w+=v.w;
    }
    *(float4*)&x2[(size_t)i*4] = s;
  } else {
    int ia = i - half;
    float4 s = *(const float4*)&p2[(size_t)ia*4];
    #pragma unroll
    for(int ks=1; ks<KSPLIT; ks++){
      float4 v = *(const float4*)&p2[(size_t)ks*total + (size_t)ia*4];
      s.x+=v.x; s.y+=v.y; s.z+=v.z; s.w+=v.w;
    }
    uint2 w;
    w.x = (unsigned)f2bf(s.x) | ((unsigned)f2bf(s.y)<<16);
    w.y = (unsigned)f2bf(s.z) | ((unsigned)f2bf(s.w)<<16);
    *(uint2*)&A2b[(size_t)ia*4] = w;
    float rs = s.x+s.y+s.z+s.w;
    #pragma unroll
    for(int o=16;o>0;o>>=1) rs += __shfl_xor(rs, o);
    if((threadIdx.x & 31) == 0) dinv2[ia>>5] = rsqrtf(rs + 1.0f);
  }
}

// ---------------- FUSED dense layer, COLUMN-SPLIT (grid = (4, B), 128 blocks): ----------------
// block (cq,b): phase 1: X[:, cq*32..+32] = dinv2 .* (act(Ain[b]) @ W cols) -> LDS (swizzled)
// phase 2: out[:, cols] = dinv2[m]*(A2b[b]@Xcols + Xcols) + bias ; stats for its 32 channels.
template<bool ACT>
__global__ void k_dense2(const float* __restrict__ Ain,
                         const unsigned short* __restrict__ Wt,
                         const unsigned short* __restrict__ A2b,
                         const float* __restrict__ dinv2, const float* __restrict__ bias,
                         const float* __restrict__ stA, const float* __restrict__ gA,
                         const float* __restrict__ beA, float invM,
                         float* __restrict__ outp, float* __restrict__ stats){
  __shared__ unsigned short Abf[128][40];   // A rows (ph1) / A2 rows (ph2) x 32-chunk
  __shared__ unsigned short Bbf[32][40];    // W cols x 32-k chunk
  __shared__ unsigned short Xt[32][136];    // [c-local][m-swizzled]
  __shared__ float ssum[32], ssq[32];
  __shared__ float lc[256];
  int tid = threadIdx.x;
  int cq = blockIdx.x, b = blockIdx.y;
  if(ACT) coef_prologue(stA, gA, beA, invM, lc, 0);
  if(tid < 32){ ssum[tid] = 0.f; ssq[tid] = 0.f; }
  __syncthreads();
  int wv = tid >> 6, lane = tid & 63;
  int quad = lane >> 4, l16 = lane & 15;

  // ---- phase 1: X_cols = act(Ain[b]) @ Wt[cq cols] ----
  float4v acc[2][2] = {};
  int ar = tid >> 1, ak = (tid & 1)*16;          // A staging: row, 16-k block
  int wr_ = tid >> 2, wk = (tid & 3)*8;          // W staging: threads 0..127
  for(int kt=0; kt<128; kt+=32){
    const float* ap = &Ain[((size_t)b*128 + ar)*128 + kt + ak];
    float va[16];
    *(float4*)&va[0]  = *(const float4*)ap;
    *(float4*)&va[4]  = *(const float4*)(ap+4);
    *(float4*)&va[8]  = *(const float4*)(ap+8);
    *(float4*)&va[12] = *(const float4*)(ap+12);
    if(ACT){
      #pragma unroll
      for(int i=0;i<16;i++){
        int c = kt+ak+i;
        va[i] = silu(lc[c]*va[i] + lc[128+c]);
      }
    }
    uint4 p0, p1;
    p0.x = (unsigned)f2bf(va[0])  | ((unsigned)f2bf(va[1])<<16);
    p0.y = (unsigned)f2bf(va[2])  | ((unsigned)f2bf(va[3])<<16);
    p0.z = (unsigned)f2bf(va[4])  | ((unsigned)f2bf(va[5])<<16);
    p0.w = (unsigned)f2bf(va[6])  | ((unsigned)f2bf(va[7])<<16);
    p1.x = (unsigned)f2bf(va[8])  | ((unsigned)f2bf(va[9])<<16);
    p1.y = (unsigned)f2bf(va[10]) | ((unsigned)f2bf(va[11])<<16);
    p1.z = (unsigned)f2bf(va[12]) | ((unsigned)f2bf(va[13])<<16);
    p1.w = (unsigned)f2bf(va[14]) | ((unsigned)f2bf(va[15])<<16);
    *(uint4*)&Abf[ar][ak]   = p0;
    *(uint4*)&Abf[ar][ak+8] = p1;
    if(tid < 128)
      *(uint4*)&Bbf[wr_][wk] = *(const uint4*)&Wt[(size_t)(cq*32 + wr_)*128 + kt + wk];
    __syncthreads();
    #pragma unroll
    for(int i=0;i<2;i++){
      short8 af = *(const short8*)&Abf[wv*32 + i*16 + l16][quad*8];
      #pragma unroll
      for(int j=0;j<2;j++){
        short8 bf = *(const short8*)&Bbf[j*16 + l16][quad*8];
        acc[i][j] = __builtin_amdgcn_mfma_f32_16x16x32_bf16(af, bf, acc[i][j], 0, 0, 0);
      }
    }
    __syncthreads();
  }
  #pragma unroll
  for(int i=0;i<2;i++){
    #pragma unroll
    for(int r=0;r<4;r++){
      int m = wv*32 + i*16 + quad*4 + r;
      float dv = dinv2[b*128 + m];
      #pragma unroll
      for(int j=0;j<2;j++){
        int cc = j*16 + l16;
        int pm = ((((m>>3) + 2*(cc&3)) & 15) << 3) | (m & 7);
        Xt[cc][pm] = f2bf(acc[i][j][r]*dv);   // same value as unsplit version
      }
    }
  }
  __syncthreads();

  // ---- phase 2: out_cols = A2b[b] @ Xcols + residual ----
  float4v acc2[2][2] = {};
  for(int n0 = 0; n0 < 128; n0 += 32){
    const unsigned short* a2p = &A2b[((size_t)b*128 + (tid>>1))*128 + n0 + (tid&1)*16];
    *(uint4*)&Abf[tid>>1][(tid&1)*16]     = *(const uint4*)a2p;
    *(uint4*)&Abf[tid>>1][(tid&1)*16 + 8] = *(const uint4*)(a2p + 8);
    __syncthreads();
    #pragma unroll
    for(int i=0;i<2;i++){
      short8 af = *(const short8*)&Abf[wv*32 + i*16 + l16][quad*8];
      #pragma unroll
      for(int j=0;j<2;j++){
        int cc = j*16 + l16;
        int pcm = ((n0>>3) + quad + 2*(cc&3)) & 15;
        short8 bf = *(const short8*)&Xt[cc][pcm<<3];
        acc2[i][j] = __builtin_amdgcn_mfma_f32_16x16x32_bf16(af, bf, acc2[i][j], 0, 0, 0);
      }
    }
    __syncthreads();
  }

  float sv[2] = {}, sq[2] = {};
  #pragma unroll
  for(int i=0;i<2;i++){
    #pragma unroll
    for(int r=0;r<4;r++){
      int m = wv*32 + i*16 + quad*4 + r;
      float dv = dinv2[b*128 + m];
      #pragma unroll
      for(int j=0;j<2;j++){
        int cc = j*16 + l16;
        int pm = ((((m>>3) + 2*(cc&3)) & 15) << 3) | (m & 7);
        float xr = u2f((unsigned)Xt[cc][pm] << 16);
        float v = dv*(acc2[i][j][r] + xr) + bias[cq*32 + cc];
        outp[((size_t)(b*128 + m))*128 + cq*32 + cc] = v;
        sv[j] += v; sq[j] += v*v;
      }
    }
  }
  #pragma unroll
  for(int j=0;j<2;j++){
    int cc = j*16 + l16;
    atomicAdd(&ssum[cc], sv[j]);
    atomicAdd(&ssq[cc], sq[j]);
  }
  __syncthreads();
  if(tid < 32){
    int slot = b & (NSLOT-1);                  // per-graph slot; channels disjoint per cq
    atomicAdd(&stats[slot*128 + cq*32 + tid], ssum[tid]);
    atomicAdd(&stats[NSLOT*128 + slot*128 + cq*32 + tid], ssq[tid]);
  }
}

// ---------------- final (merged): per-graph BN+SiLU reduce, logits, log-softmax ----------------
__global__ void k_final(const float* __restrict__ dTa, const float* __restrict__ dTb,
                        const float* __restrict__ stA, const float* __restrict__ gA,
                        const float* __restrict__ beA,
                        const float* __restrict__ stB, const float* __restrict__ gB,
                        const float* __restrict__ beB, float invMc,
                        const float* __restrict__ wl, const float* __restrict__ bl,
                        float* __restrict__ out, int K1n, int Cc, float inv_k2,
                        int OUTc, int zero_idx){
  __shared__ float lcA[256], lcB[256];
  __shared__ float red[256];
  __shared__ float gsh[128];
  __shared__ float logits[32];
  __shared__ float mred, lred;
  coef_prologue(stA, gA, beA, invMc, lcA, 0);
  coef_prologue(stB, gB, beB, invMc, lcB, 128);
  __syncthreads();
  int b = blockIdx.x;
  int tid = threadIdx.x;
  int c = tid & 127, rh = tid >> 7;   // 2 rows in flight
  const float* pa = dTa + (size_t)b*K1n*Cc;
  const float* pb = dTb + (size_t)b*K1n*Cc;
  float sa = lcA[c], ha = lcA[128+c], sb = lcB[c], hb = lcB[128+c];
  float acc = 0.f;
  for(int r = rh; r < K1n; r += 2){
    float ya = sa*pa[(size_t)r*Cc + c] + ha;
    float yb = sb*pb[(size_t)r*Cc + c] + hb;
    acc += silu(ya) + silu(yb);
  }
  red[tid] = acc;
  __syncthreads();
  if(tid < 128) gsh[tid] = (red[tid] + red[tid+128]) * inv_k2;
  __syncthreads();
  if(tid < OUTc){
    float l = bl[tid];
    for(int d2=0; d2<Cc; d2++) l += gsh[d2]*wl[d2*OUTc + tid];
    logits[tid] = l;
  }
  __syncthreads();
  if(tid==0){
    float m = -1e30f;
    for(int o=0;o<OUTc;o++) m = fmaxf(m, logits[o]);
    float s = 0.f;
    for(int o=0;o<OUTc;o++) s += __expf(logits[o]-m);
    mred = m; lred = logf(s);
  }
  __syncthreads();
  if(tid < OUTc) out[b*OUTc + tid] = logits[tid] - mred - lred;
  if(b==0 && tid==0 && zero_idx >= 0) out[zero_idx] = 0.f;
}

// ---------------- launch ----------------
extern "C" void kernel_launch(void* const* d_in, const int* in_sizes, int n_in,
                              void* d_out, int out_size, void* d_ws, size_t ws_size,
                              hipStream_t stream){
  const float* x    = (const float*)d_in[0];
  const int*   ei   = (const int*)d_in[1];
  const float* w1a  = (const float*)d_in[4];
  const float* b1a  = (const float*)d_in[5];
  const float* g1a  = (const float*)d_in[6];
  const float* be1a = (const float*)d_in[7];
  const float* w1b  = (const float*)d_in[8];
  const float* b1b  = (const float*)d_in[9];
  const float* g1b  = (const float*)d_in[10];
  const float* be1b = (const float*)d_in[11];
  const float* wp1  = (const float*)d_in[12];
  const float* bp1  = (const float*)d_in[13];
  const float* w2a  = (const float*)d_in[14];
  const float* b2a  = (const float*)d_in[15];
  const float* g2a  = (const float*)d_in[16];
  const float* be2a = (const float*)d_in[17];
  const float* w2b  = (const float*)d_in[18];
  const float* b2b  = (const float*)d_in[19];
  const float* g2b  = (const float*)d_in[20];
  const float* be2b = (const float*)d_in[21];
  const float* wl   = (const float*)d_in[24];
  const float* bl   = (const float*)d_in[25];
  float* out = (float*)d_out;

  const int C_   = in_sizes[5];            // 128
  const int CIN_ = in_sizes[4]/C_;         // 64
  const int N    = in_sizes[0]/CIN_;       // 32768
  const int E    = in_sizes[1]/2;          // 524288
  const int B_   = in_sizes[3]-1;          // 32
  const int NPG_ = N/B_;                   // 1024
  const int K1_  = in_sizes[13];           // 128
  const int K2_  = in_sizes[23];           // 32
  const int OUTc = in_sizes[25];           // 10
  const int M2   = B_*K1_;                 // 4096
  const int total = M2*C_;                 // 524288
  const int NX   = N*CIN_;                 // 2097152

  const int* srcI = ei;
  const int* dstI = ei + E;

  float* ws = (float*)d_ws;
  size_t o = 0;
  unsigned short* bufW = (unsigned short*)(ws + o); o += (size_t)N*C_/2;   // bf16 gemm out
  unsigned short* bufA = (unsigned short*)(ws + o); o += (size_t)N*C_/2;   // 1a gather out (bf16)
  unsigned short* bufB = (unsigned short*)(ws + o); o += (size_t)N*C_/2;   // 1b gather out (bf16)
  unsigned short* bufS = (unsigned short*)(ws + o); o += (size_t)N*C_/2;   // s (bf16)
  unsigned short* bufT = (unsigned short*)(ws + o); o += (size_t)N*C_/2;   // t = A s (bf16)
  unsigned short* bufH = (unsigned short*)(ws + o); o += (size_t)N*C_/2;   // fused h (bf16)
  unsigned short* xbf  = (unsigned short*)(ws + o); o += (size_t)NX/2 + 64; // x (bf16)
  float* x2    = ws + o; o += (size_t)total;
  unsigned short* A2b = (unsigned short*)(ws + o); o += (size_t)total/2;   // A2 (bf16)
  float* dinv2 = ws + o; o += (size_t)M2;
  // zero block: 4 x NSLOT-slot stats + cursor — ONE memset
  float* st1a  = ws + o; o += 2*NSLOT*128;
  float* st1b  = ws + o; o += 2*NSLOT*128;
  float* stDa  = ws + o; o += 2*NSLOT*128;
  float* stDb  = ws + o; o += 2*NSLOT*128;
  int* cursor  = (int*)(ws + o); o += (size_t)N;
  float* part  = ws + o; o += (size_t)KSPLIT*total;
  float* part2 = ws + o; o += (size_t)KSPLIT*total;
  float* dTa = part + (size_t)total;
  float* dTb = part + 2*(size_t)total;
  unsigned short* wt1a = (unsigned short*)(ws + o); o += (size_t)CIN_*C_/2 + 64;
  unsigned short* wt1b = (unsigned short*)(ws + o); o += (size_t)C_*C_/2 + 64;
  unsigned short* wtp1 = (unsigned short*)(ws + o); o += (size_t)C_*C_/2 + 64;
  unsigned short* wt2a = (unsigned short*)(ws + o); o += (size_t)C_*C_/2 + 64;
  unsigned short* wt2b = (unsigned short*)(ws + o); o += (size_t)C_*C_/2 + 64;
  int* esrc    = (int*)(ws + o); o += (size_t)N*ELL_ST;
  (void)ws_size; (void)n_in;

  dim3 blk256(256);
  auto g1 = [](int n){ return dim3((unsigned)((n+255)/256)); };
  const float invN = 1.0f/N, invM2 = 1.0f/M2;

  // ---- setup: one memset (stats x4 + cursor), then ELL fill + wt transposes + x->bf16 ----
  hipMemsetAsync(st1a, 0, (size_t)4*2*NSLOT*128*sizeof(float) + (size_t)N*sizeof(int), stream);
  k_fill_wt<<<g1(E + CIN_*C_ + 4*C_*C_ + NX), blk256, 0, stream>>>(srcI, dstI, cursor, esrc, E,
      w1a, w1b, wp1, w2a, w2b, wt1a, wt1b, wtp1, wt2a, wt2b, x, xbf, NX, CIN_);

  dim3 gath((unsigned)(N/4));
  dim3 gmm((unsigned)(N/64));

  // ---- layer 1a (bf16 A pass-through) ----
  k_gemm_mfma<true><<<gmm, blk256, 0, stream>>>(xbf, nullptr, wt1a, bufW, nullptr, N, CIN_, cursor,
      nullptr, nullptr, nullptr, nullptr, nullptr, nullptr, nullptr, 0.f);
  k_gather<false,true,true,true><<<gath, blk256, 0, stream>>>(cursor, esrc, bufW, b1a, (float*)bufA, st1a);

  // ---- layer 1b (coef1a inlined; bf16 A) ----
  k_gemm_mfma<true><<<gmm, blk256, 0, stream>>>(bufA, nullptr, wt1b, bufW, nullptr, N, C_, cursor,
      nullptr, st1a, g1a, be1a, nullptr, nullptr, nullptr, invN);
  k_gather<false,true,true,true><<<gath, blk256, 0, stream>>>(cursor, esrc, bufW, b1b, (float*)bufB, st1b);

  // ---- pool: s = softmax(gcn(h, wp1, bp1)) bf16; h (fused act) dumped bf16 as side-product ----
  k_gemm_mfma<true><<<gmm, blk256, 0, stream>>>(bufA, bufB, wtp1, bufW, bufH, N, C_, cursor,
      nullptr, st1a, g1a, be1a, st1b, g1b, be1b, invN);
  k_gather<true,true,false,true><<<gath, blk256, 0, stream>>>(cursor, esrc, bufW, bp1, (float*)bufS, nullptr);
  k_gather<false,false,false,true><<<gath, blk256, 0, stream>>>(cursor, esrc, bufS, nullptr, (float*)bufT, nullptr);

  // x2 = s^T h (z=0, from bf16 H) ; A2 = s^T t (z=1) — ONE MFMA launch, then reduce + dinv2
  k_pool2<<<dim3(KSPLIT, B_, 2), blk256, 0, stream>>>(bufS, bufH, bufT,
      part, part2, NPG_, B_);
  k_pool_reduce2<<<g1(total/2), blk256, 0, stream>>>(part, part2, x2, A2b, dinv2, total);

  // ---- dense stack: TWO fused kernels, COLUMN-SPLIT (4x occupancy) ----
  k_dense2<false><<<dim3(4, (unsigned)B_), blk256, 0, stream>>>(x2, wt2a, A2b, dinv2, b2a,
      nullptr, nullptr, nullptr, 0.f, dTa, stDa);
  k_dense2<true><<<dim3(4, (unsigned)B_), blk256, 0, stream>>>(dTa, wt2b, A2b, dinv2, b2b,
      stDa, g2a, be2a, invM2, dTb, stDb);

  // ---- final: one kernel per graph — BN+SiLU reduce, logits, log-softmax ----
  int zero_idx = (out_size > B_*OUTc) ? B_*OUTc : -1;
  k_final<<<dim3((unsigned)B_), blk256, 0, stream>>>(dTa, dTb,
      stDa, g2a, be2a, stDb, g2b, be2b, invM2, wl, bl, out, K1_, C_, 1.0f/K2_,
      OUTc, zero_idx);
}